// Round 2
// baseline (5610.770 us; speedup 1.0000x reference)
//
#include <hip/hip_runtime.h>
#include <cstddef>
#include <cstdint>

// ---- model dims ----
#define L_TOK 392
#define BATCH 8
#define DM    768
#define ED    1536
#define NST   16
#define DTR   48
#define ROWS  (BATCH * L_TOK)   // 3136

// Workspace layout (BYTES, all 16B aligned), total = 49,172,480 B (~47 MB):
//  X    fp32 [ROWS*DM]   9,633,792 B   residual (persistent across layers)
//  XC   bf16 [ROWS*ED]   9,633,792 B   conv input; reused for im2col patches & y
//  Z    bf16 [ROWS*ED]   9,633,792 B   gate half of in_proj
//  XIN  bf16 [ROWS*ED]   9,633,792 B   conv+silu output
//  DEL  bf16 [ROWS*ED]   9,633,792 B   delta; front 4.8MB doubles as xn buffer
//  DBC  fp32 [ROWS*80]   1,003,520 B
// (round-1 used 107 MB with no ws_size check -> overran d_ws and corrupted the
//  harness's pristine input copies; this layout is the fix)

typedef unsigned short ushortT;

__device__ __forceinline__ float bf2f(ushortT u) {
    union { unsigned int i; float f; } v; v.i = ((unsigned int)u) << 16; return v.f;
}
__device__ __forceinline__ ushortT f2bf(float f) {
    union { float f; unsigned int i; } v; v.f = f;
    unsigned int r = v.i + 0x7FFFu + ((v.i >> 16) & 1u);   // round-nearest-even
    return (ushortT)(r >> 16);
}

// ----------------------------------------------------------------------------
// Generic tiled GEMM: C[M,N] (epi) A[M,K](lda) @ W[N,K](ldw)^T
// 64x64 tile, BK=16, 256 threads, 4x4 microtile. A may be bf16 or fp32,
// C may be bf16 or fp32; W (model weights) always fp32.
// Requires K % 16 == 0; M % 64 == 0 at all call sites.
// ----------------------------------------------------------------------------
enum { EPI_STORE = 0, EPI_BIAS = 1, EPI_BIAS_SOFTPLUS = 2, EPI_ADD = 3 };

template <int EPI, bool A_BF, bool C_BF>
__global__ __launch_bounds__(256)
void gemm_nt(const void* __restrict__ Av, int lda,
             const float* __restrict__ W, int ldw,
             const float* __restrict__ bias,
             void* __restrict__ Cv, int ldc,
             int M, int N, int K)
{
    __shared__ float As[16][68];   // [k][m], pad to 68 keeps float4 alignment
    __shared__ float Bs[16][68];   // [k][n]
    const int tid = threadIdx.x;
    const int tx  = tid & 15;      // -> 4 cols
    const int ty  = tid >> 4;      // -> 4 rows
    const int bm  = blockIdx.y * 64;
    const int bn  = blockIdx.x * 64;
    const int lr  = tid >> 2;        // 0..63 tile row
    const int lk  = (tid & 3) * 4;   // 0,4,8,12

    float acc[4][4] = {};

    for (int k0 = 0; k0 < K; k0 += 16) {
        float a0 = 0.f, a1 = 0.f, a2 = 0.f, a3 = 0.f;
        float w0 = 0.f, w1 = 0.f, w2 = 0.f, w3 = 0.f;
        int ga = bm + lr;
        if (ga < M) {
            if (A_BF) {
                const ushortT* A = (const ushortT*)Av;
                ushort4 t = *(const ushort4*)(A + (size_t)ga * lda + k0 + lk);
                a0 = bf2f(t.x); a1 = bf2f(t.y); a2 = bf2f(t.z); a3 = bf2f(t.w);
            } else {
                const float* A = (const float*)Av;
                float4 t = *(const float4*)(A + (size_t)ga * lda + k0 + lk);
                a0 = t.x; a1 = t.y; a2 = t.z; a3 = t.w;
            }
        }
        int gw = bn + lr;
        if (gw < N) {
            float4 t = *(const float4*)(W + (size_t)gw * ldw + k0 + lk);
            w0 = t.x; w1 = t.y; w2 = t.z; w3 = t.w;
        }
        As[lk + 0][lr] = a0; As[lk + 1][lr] = a1;
        As[lk + 2][lr] = a2; As[lk + 3][lr] = a3;
        Bs[lk + 0][lr] = w0; Bs[lk + 1][lr] = w1;
        Bs[lk + 2][lr] = w2; Bs[lk + 3][lr] = w3;
        __syncthreads();
#pragma unroll
        for (int k = 0; k < 16; ++k) {
            float4 a4 = *(const float4*)&As[k][ty * 4];
            float4 b4 = *(const float4*)&Bs[k][tx * 4];
            float a[4] = {a4.x, a4.y, a4.z, a4.w};
            float b[4] = {b4.x, b4.y, b4.z, b4.w};
#pragma unroll
            for (int i = 0; i < 4; ++i)
#pragma unroll
                for (int j = 0; j < 4; ++j)
                    acc[i][j] += a[i] * b[j];
        }
        __syncthreads();
    }

#pragma unroll
    for (int i = 0; i < 4; ++i) {
        int gm = bm + ty * 4 + i;
        if (gm >= M) continue;
#pragma unroll
        for (int j = 0; j < 4; ++j) {
            int gn = bn + tx * 4 + j;
            if (gn >= N) continue;
            float v = acc[i][j];
            if (EPI == EPI_BIAS) v += bias[gn];
            if (EPI == EPI_BIAS_SOFTPLUS) {
                v += bias[gn];
                v = fmaxf(v, 0.f) + log1pf(expf(-fabsf(v)));  // softplus
            }
            size_t off = (size_t)gm * ldc + gn;
            if (C_BF) {
                ((ushortT*)Cv)[off] = f2bf(v);
            } else {
                float* p = (float*)Cv + off;
                *p = (EPI == EPI_ADD) ? v + *p : v;
            }
        }
    }
}

// ----------------------------------------------------------------------------
// RMSNorm: xn[r,:] = x[r,:] * rsqrt(mean(x^2)+1e-5) * w   (768 per row, bf16 out)
// ----------------------------------------------------------------------------
__global__ __launch_bounds__(256)
void rmsnorm_kernel(const float* __restrict__ x, const float* __restrict__ w,
                    ushortT* __restrict__ xn)
{
    int r = blockIdx.x;
    const float* xr = x + (size_t)r * DM;
    float v[3];
    float s = 0.f;
#pragma unroll
    for (int i = 0; i < 3; ++i) {
        v[i] = xr[threadIdx.x + i * 256];
        s += v[i] * v[i];
    }
#pragma unroll
    for (int o = 32; o > 0; o >>= 1) s += __shfl_down(s, o, 64);
    __shared__ float wsum[4];
    __shared__ float scale_s;
    int wave = threadIdx.x >> 6;
    if ((threadIdx.x & 63) == 0) wsum[wave] = s;
    __syncthreads();
    if (threadIdx.x == 0) {
        float t = wsum[0] + wsum[1] + wsum[2] + wsum[3];
        scale_s = rsqrtf(t * (1.f / 768.f) + 1e-5f);
    }
    __syncthreads();
    float sc = scale_s;
#pragma unroll
    for (int i = 0; i < 3; ++i) {
        int d = threadIdx.x + i * 256;
        xn[(size_t)r * DM + d] = f2bf(v[i] * sc * w[d]);
    }
}

// ----------------------------------------------------------------------------
// Causal depthwise conv (width 4) + bias + silu.  xc[b,l,e] (bf16) -> xin (bf16)
// ----------------------------------------------------------------------------
__global__ __launch_bounds__(256)
void conv_silu_kernel(const ushortT* __restrict__ xc, const float* __restrict__ cw,
                      const float* __restrict__ cb, ushortT* __restrict__ xin)
{
    int idx = blockIdx.x * 256 + threadIdx.x;
    if (idx >= ROWS * ED) return;
    int e = idx % ED;
    int r = idx / ED;
    int l = r % L_TOK;
    float w0 = cw[e * 4 + 0], w1 = cw[e * 4 + 1];
    float w2 = cw[e * 4 + 2], w3 = cw[e * 4 + 3];
    const ushortT* base = xc + (size_t)r * ED + e;
    float acc = cb[e] + w3 * bf2f(base[0]);
    if (l >= 1) acc += w2 * bf2f(base[-(ptrdiff_t)ED]);
    if (l >= 2) acc += w1 * bf2f(base[-(ptrdiff_t)(2 * ED)]);
    if (l >= 3) acc += w0 * bf2f(base[-(ptrdiff_t)(3 * ED)]);
    xin[(size_t)r * ED + e] = f2bf(acc / (1.f + __expf(-acc)));  // silu
}

// ----------------------------------------------------------------------------
// Selective scan, fused with +D*xin and *silu(z).  All tensor I/O bf16 except
// DBC (fp32).  Block = 256 threads = 16 channels x 16 states.
// ----------------------------------------------------------------------------
__global__ __launch_bounds__(256)
void scan_kernel(const ushortT* __restrict__ delta, const ushortT* __restrict__ xin,
                 const float* __restrict__ dbc, const ushortT* __restrict__ zb,
                 const float* __restrict__ a_log, const float* __restrict__ dvec,
                 ushortT* __restrict__ y)
{
    int tid = threadIdx.x;
    int n  = tid & 15;
    int el = tid >> 4;
    int b  = blockIdx.x / (ED / 16);
    int e  = (blockIdx.x % (ED / 16)) * 16 + el;

    float a   = -expf(a_log[e * NST + n]);   // A = -exp(A_log)
    float dcf = dvec[e];
    float h = 0.f;

    int r = b * L_TOK;
    float dl = bf2f(delta[(size_t)r * ED + e]);
    float xi = bf2f(xin[(size_t)r * ED + e]);
    float Bn = dbc[r * 80 + 48 + n];
    float Cn = dbc[r * 80 + 64 + n];
    float z  = bf2f(zb[(size_t)r * ED + e]);

    for (int l = 0; l < L_TOK; ++l) {
        int rn = r + 1;
        float dl2 = 0.f, xi2 = 0.f, Bn2 = 0.f, Cn2 = 0.f, z2 = 0.f;
        if (l + 1 < L_TOK) {   // prefetch next step
            dl2 = bf2f(delta[(size_t)rn * ED + e]);
            xi2 = bf2f(xin[(size_t)rn * ED + e]);
            Bn2 = dbc[rn * 80 + 48 + n];
            Cn2 = dbc[rn * 80 + 64 + n];
            z2  = bf2f(zb[(size_t)rn * ED + e]);
        }
        float dA = __expf(dl * a);
        h = dA * h + dl * xi * Bn;
        float p = h * Cn;
        p += __shfl_xor(p, 1);
        p += __shfl_xor(p, 2);
        p += __shfl_xor(p, 4);
        p += __shfl_xor(p, 8);
        if (n == 0) {
            float yv = p + dcf * xi;
            float sz = z / (1.f + __expf(-z));
            y[(size_t)r * ED + e] = f2bf(yv * sz);
        }
        dl = dl2; xi = xi2; Bn = Bn2; Cn = Cn2; z = z2;
        r = rn;
    }
}

// ----------------------------------------------------------------------------
// im2col for patch embed: P[r, k] (bf16) with r=(b, img, patch), k=(c,ph,pw)
// ----------------------------------------------------------------------------
__global__ __launch_bounds__(256)
void im2col_kernel(const float* __restrict__ rgb, const float* __restrict__ timg,
                   ushortT* __restrict__ P)
{
    int idx = blockIdx.x * 256 + threadIdx.x;
    if (idx >= ROWS * DM) return;
    int k = idx % DM;
    int r = idx / DM;
    int b = r / L_TOK;
    int l = r % L_TOK;
    const float* img = (l < 196) ? rgb : timg;
    int p  = (l < 196) ? l : l - 196;
    int py = p / 14, px = p % 14;
    int c  = k >> 8;
    int ph = (k >> 4) & 15;
    int pw = k & 15;
    P[idx] = f2bf(img[(((size_t)b * 3 + c) * 224 + (py * 16 + ph)) * 224 + (px * 16 + pw)]);
}

// ----------------------------------------------------------------------------
// Output: out[(l*768 + d)*8 + b] = x[b, l, d]   (the transpose(3,1,2,0) view)
// ----------------------------------------------------------------------------
__global__ __launch_bounds__(256)
void out_transpose_kernel(const float* __restrict__ x, float* __restrict__ out)
{
    int idx = blockIdx.x * 256 + threadIdx.x;
    if (idx >= ROWS * DM) return;
    int b = idx & 7;
    int d = (idx >> 3) % DM;
    int l = idx / (8 * DM);
    out[idx] = x[((size_t)(b * L_TOK + l)) * DM + d];
}

// ----------------------------------------------------------------------------
extern "C" void kernel_launch(void* const* d_in, const int* in_sizes, int n_in,
                              void* d_out, int out_size, void* d_ws, size_t ws_size,
                              hipStream_t stream)
{
    (void)in_sizes; (void)n_in; (void)out_size; (void)ws_size;

    const float* rgb  = (const float*)d_in[0];
    const float* timg = (const float*)d_in[1];
    const float* pe_w = (const float*)d_in[2];   // [768, 3,16,16] -> [768][768]
    const float* pe_b = (const float*)d_in[3];
    const float* in_w = (const float*)d_in[4];   // [8, 3072, 768]
    const float* cw   = (const float*)d_in[5];   // [8, 1536, 1, 4]
    const float* cb   = (const float*)d_in[6];   // [8, 1536]
    const float* xw   = (const float*)d_in[7];   // [8, 80, 1536]
    const float* dtw  = (const float*)d_in[8];   // [8, 1536, 48]
    const float* dtb  = (const float*)d_in[9];   // [8, 1536]
    const float* alog = (const float*)d_in[10];  // [8, 1536, 16]
    const float* dvec = (const float*)d_in[11];  // [8, 1536]
    const float* ow   = (const float*)d_in[12];  // [8, 768, 1536]
    const float* nw   = (const float*)d_in[13];  // [8, 768]

    char* p = (char*)d_ws;
    float*   X   = (float*)p;    p += (size_t)ROWS * DM * 4;   // 9,633,792 B
    ushortT* XC  = (ushortT*)p;  p += (size_t)ROWS * ED * 2;   // conv-in / patches / y
    ushortT* Zb  = (ushortT*)p;  p += (size_t)ROWS * ED * 2;
    ushortT* XIN = (ushortT*)p;  p += (size_t)ROWS * ED * 2;
    ushortT* DEL = (ushortT*)p;  p += (size_t)ROWS * ED * 2;   // delta; front = xn
    float*   DBC = (float*)p;    p += (size_t)ROWS * 80 * 4;
    ushortT* XN  = DEL;          // overlay: xn dead before delta is written

    dim3 b256(256);

    // ---- patch embed: im2col (bf16) into XC, then GEMM+bias -> X (fp32) ----
    im2col_kernel<<<(ROWS * DM + 255) / 256, b256, 0, stream>>>(rgb, timg, XC);
    gemm_nt<EPI_BIAS, true, false><<<dim3(DM / 64, ROWS / 64), b256, 0, stream>>>(
        XC, DM, pe_w, DM, pe_b, X, DM, ROWS, DM, DM);

    for (int i = 0; i < 8; ++i) {
        const float* in_wi = in_w + (size_t)i * 2 * ED * DM;
        const float* cwi   = cw   + (size_t)i * ED * 4;
        const float* cbi   = cb   + (size_t)i * ED;
        const float* xwi   = xw   + (size_t)i * 80 * ED;
        const float* dtwi  = dtw  + (size_t)i * ED * DTR;
        const float* dtbi  = dtb  + (size_t)i * ED;
        const float* ali   = alog + (size_t)i * ED * NST;
        const float* dvi   = dvec + (size_t)i * ED;
        const float* owi   = ow   + (size_t)i * DM * ED;
        const float* nwi   = nw   + (size_t)i * DM;

        // xn = rmsnorm(x)  -> XN (bf16, overlaid on DEL)
        rmsnorm_kernel<<<ROWS, b256, 0, stream>>>(X, nwi, XN);
        // xc = xn @ in_w[:ED]^T ; z = xn @ in_w[ED:]^T
        gemm_nt<EPI_STORE, true, true><<<dim3(ED / 64, ROWS / 64), b256, 0, stream>>>(
            XN, DM, in_wi, DM, nullptr, XC, ED, ROWS, ED, DM);
        gemm_nt<EPI_STORE, true, true><<<dim3(ED / 64, ROWS / 64), b256, 0, stream>>>(
            XN, DM, in_wi + (size_t)ED * DM, DM, nullptr, Zb, ED, ROWS, ED, DM);
        // xin = silu(causal_conv(xc) + cb)
        conv_silu_kernel<<<(ROWS * ED + 255) / 256, b256, 0, stream>>>(
            XC, cwi, cbi, XIN);
        // dbc = xin @ xw^T  -> DBC fp32 [3136,80]
        gemm_nt<EPI_STORE, true, false><<<dim3(2, ROWS / 64), b256, 0, stream>>>(
            XIN, ED, xwi, ED, nullptr, DBC, 80, ROWS, 80, ED);
        // delta = softplus(dbc[:, :48] @ dtw^T + dtb) -> DEL bf16
        gemm_nt<EPI_BIAS_SOFTPLUS, false, true><<<dim3(ED / 64, ROWS / 64), b256, 0, stream>>>(
            DBC, 80, dtwi, DTR, dtbi, DEL, ED, ROWS, ED, DTR);
        // y = scan(...) fused +D*xin, *silu(z)  -> XC (bf16, conv-in is dead)
        scan_kernel<<<BATCH * (ED / 16), b256, 0, stream>>>(
            DEL, XIN, DBC, Zb, ali, dvi, XC);
        // x += y @ ow^T
        gemm_nt<EPI_ADD, true, false><<<dim3(DM / 64, ROWS / 64), b256, 0, stream>>>(
            XC, ED, owi, ED, nullptr, X, DM, ROWS, DM, ED);
    }

    out_transpose_kernel<<<(ROWS * DM + 255) / 256, b256, 0, stream>>>(
        X, (float*)d_out);
}

// Round 3
// 3768.122 us; speedup vs baseline: 1.4890x; 1.4890x over previous
//
#include <hip/hip_runtime.h>
#include <cstddef>
#include <cstdint>

// ---- model dims ----
#define L_TOK 392
#define BATCH 8
#define DM    768
#define ED    1536
#define NST   16
#define DTR   48
#define ROWS  (BATCH * L_TOK)   // 3136

// Workspace layout (BYTES, all 16B aligned), total = 49,172,480 B (~47 MB):
//  X    fp32 [ROWS*DM]   residual (persistent across layers)
//  XC   bf16 [ROWS*ED]   conv input; reused for im2col patches & y
//  Z    bf16 [ROWS*ED]   gate half of in_proj
//  XIN  bf16 [ROWS*ED]   conv+silu output
//  DEL  bf16 [ROWS*ED]   delta; front 4.8MB doubles as xn buffer
//  DBC  fp32 [ROWS*80]
// (round-1 overran d_ws at 107MB and corrupted pristine inputs; keep <= 47MB)

typedef unsigned short ushortT;
typedef __bf16 bf16x8 __attribute__((ext_vector_type(8)));
typedef unsigned short us8 __attribute__((ext_vector_type(8)));
typedef unsigned short us4 __attribute__((ext_vector_type(4)));
typedef float f32x4 __attribute__((ext_vector_type(4)));

__device__ __forceinline__ float bf2f(ushortT u) {
    union { unsigned int i; float f; } v; v.i = ((unsigned int)u) << 16; return v.f;
}
__device__ __forceinline__ ushortT f2bf(float f) {
    union { float f; unsigned int i; } v; v.f = f;
    unsigned int r = v.i + 0x7FFFu + ((v.i >> 16) & 1u);   // round-nearest-even
    return (ushortT)(r >> 16);
}

enum { EPI_STORE = 0, EPI_BIAS = 1, EPI_BIAS_SOFTPLUS = 2, EPI_ADD = 3 };

// ----------------------------------------------------------------------------
// MFMA GEMM: C[M,N] (epi)= A[M,K](bf16, lda) @ W[N,K](fp32, ldw)^T
// 128x128 tile, BK=32, 256 threads = 4 waves in 2x2, each wave 64x64 via
// 4x4 v_mfma_f32_16x16x32_bf16.  W converted fp32->bf16 during LDS staging.
// Requires N % 128 == 0, K % 32 == 0, lda % 8 == 0; M guarded.
// LDS stride 40 ushorts (80B): frag ds_read_b128 lands 2-way (free, m136).
// Layouts (HW-verified per guide): A/B frag [row=lane&15][k=quad*8+j],
// C/D: col=lane&15, row=quad*4+reg.
// ----------------------------------------------------------------------------
template <int EPI, bool C_BF>
__global__ __launch_bounds__(256)
void gemm_mfma(const ushortT* __restrict__ A, int lda,
               const float* __restrict__ W, int ldw,
               const float* __restrict__ bias,
               void* __restrict__ Cv, int ldc,
               int M, int N, int K)
{
    __shared__ ushortT As[128 * 40];
    __shared__ ushortT Ws[128 * 40];

    const int tid  = threadIdx.x;
    const int lane = tid & 63;
    const int wave = tid >> 6;
    const int wm   = wave >> 1;        // 0..1
    const int wn   = wave & 1;         // 0..1
    const int quad = lane >> 4;        // 0..3
    const int l16  = lane & 15;        // 0..15

    const int m0 = blockIdx.y * 128;
    const int n0 = blockIdx.x * 128;

    // staging indices
    const int ar   = tid >> 1;         // 0..127  A row
    const int ahalf= tid & 1;          // 16-elem half
    const int wr   = tid >> 3;         // 0..31   W row (x4 iters)
    const int wc   = (tid & 7) * 4;    // float4 col

    f32x4 acc[4][4] = {};

    for (int k0 = 0; k0 < K; k0 += 32) {
        // ---- stage A tile (bf16 -> LDS) ----
        us8 a0 = {0,0,0,0,0,0,0,0}, a1 = {0,0,0,0,0,0,0,0};
        int gm = m0 + ar;
        if (gm < M) {
            const ushortT* src = A + (size_t)gm * lda + k0 + ahalf * 16;
            a0 = *(const us8*)(src);
            a1 = *(const us8*)(src + 8);
        }
        *(us8*)&As[ar * 40 + ahalf * 16]     = a0;
        *(us8*)&As[ar * 40 + ahalf * 16 + 8] = a1;
        // ---- stage W tile (fp32 -> bf16 -> LDS) ----
#pragma unroll
        for (int it = 0; it < 4; ++it) {
            int row = it * 32 + wr;
            float4 f = *(const float4*)(W + (size_t)(n0 + row) * ldw + k0 + wc);
            us4 h; h.x = f2bf(f.x); h.y = f2bf(f.y); h.z = f2bf(f.z); h.w = f2bf(f.w);
            *(us4*)&Ws[row * 40 + wc] = h;
        }
        __syncthreads();

        bf16x8 af[4], bw[4];
#pragma unroll
        for (int t = 0; t < 4; ++t) {
            us8 ta = *(const us8*)&As[(wm * 64 + t * 16 + l16) * 40 + quad * 8];
            af[t] = __builtin_bit_cast(bf16x8, ta);
            us8 tb = *(const us8*)&Ws[(wn * 64 + t * 16 + l16) * 40 + quad * 8];
            bw[t] = __builtin_bit_cast(bf16x8, tb);
        }
#pragma unroll
        for (int i = 0; i < 4; ++i)
#pragma unroll
            for (int j = 0; j < 4; ++j)
                acc[i][j] = __builtin_amdgcn_mfma_f32_16x16x32_bf16(
                    af[i], bw[j], acc[i][j], 0, 0, 0);
        __syncthreads();
    }

    // ---- epilogue ----
#pragma unroll
    for (int i = 0; i < 4; ++i) {
#pragma unroll
        for (int r = 0; r < 4; ++r) {
            int gm = m0 + wm * 64 + i * 16 + quad * 4 + r;
            if (gm >= M) continue;
#pragma unroll
            for (int j = 0; j < 4; ++j) {
                int gn = n0 + wn * 64 + j * 16 + l16;
                float v = acc[i][j][r];
                if (EPI == EPI_BIAS) v += bias[gn];
                size_t off = (size_t)gm * ldc + gn;
                if (C_BF) {
                    ((ushortT*)Cv)[off] = f2bf(v);
                } else {
                    float* p = (float*)Cv + off;
                    *p = (EPI == EPI_ADD) ? v + *p : v;
                }
            }
        }
    }
}

// ----------------------------------------------------------------------------
// VALU tiled GEMM for the small shapes (x_proj N=80, dt_proj K=48).
// C[M,N] (epi) A @ W^T; 64x64 tile, BK=16.
// ----------------------------------------------------------------------------
template <int EPI, bool A_BF, bool C_BF>
__global__ __launch_bounds__(256)
void gemm_nt(const void* __restrict__ Av, int lda,
             const float* __restrict__ W, int ldw,
             const float* __restrict__ bias,
             void* __restrict__ Cv, int ldc,
             int M, int N, int K)
{
    __shared__ float As[16][68];
    __shared__ float Bs[16][68];
    const int tid = threadIdx.x;
    const int tx  = tid & 15;
    const int ty  = tid >> 4;
    const int bm  = blockIdx.y * 64;
    const int bn  = blockIdx.x * 64;
    const int lr  = tid >> 2;
    const int lk  = (tid & 3) * 4;

    float acc[4][4] = {};

    for (int k0 = 0; k0 < K; k0 += 16) {
        float a0 = 0.f, a1 = 0.f, a2 = 0.f, a3 = 0.f;
        float w0 = 0.f, w1 = 0.f, w2 = 0.f, w3 = 0.f;
        int ga = bm + lr;
        if (ga < M) {
            if (A_BF) {
                const ushortT* A = (const ushortT*)Av;
                ushort4 t = *(const ushort4*)(A + (size_t)ga * lda + k0 + lk);
                a0 = bf2f(t.x); a1 = bf2f(t.y); a2 = bf2f(t.z); a3 = bf2f(t.w);
            } else {
                const float* A = (const float*)Av;
                float4 t = *(const float4*)(A + (size_t)ga * lda + k0 + lk);
                a0 = t.x; a1 = t.y; a2 = t.z; a3 = t.w;
            }
        }
        int gw = bn + lr;
        if (gw < N) {
            float4 t = *(const float4*)(W + (size_t)gw * ldw + k0 + lk);
            w0 = t.x; w1 = t.y; w2 = t.z; w3 = t.w;
        }
        As[lk + 0][lr] = a0; As[lk + 1][lr] = a1;
        As[lk + 2][lr] = a2; As[lk + 3][lr] = a3;
        Bs[lk + 0][lr] = w0; Bs[lk + 1][lr] = w1;
        Bs[lk + 2][lr] = w2; Bs[lk + 3][lr] = w3;
        __syncthreads();
#pragma unroll
        for (int k = 0; k < 16; ++k) {
            float4 a4 = *(const float4*)&As[k][ty * 4];
            float4 b4 = *(const float4*)&Bs[k][tx * 4];
            float a[4] = {a4.x, a4.y, a4.z, a4.w};
            float b[4] = {b4.x, b4.y, b4.z, b4.w};
#pragma unroll
            for (int i = 0; i < 4; ++i)
#pragma unroll
                for (int j = 0; j < 4; ++j)
                    acc[i][j] += a[i] * b[j];
        }
        __syncthreads();
    }

#pragma unroll
    for (int i = 0; i < 4; ++i) {
        int gm = bm + ty * 4 + i;
        if (gm >= M) continue;
#pragma unroll
        for (int j = 0; j < 4; ++j) {
            int gn = bn + tx * 4 + j;
            if (gn >= N) continue;
            float v = acc[i][j];
            if (EPI == EPI_BIAS) v += bias[gn];
            if (EPI == EPI_BIAS_SOFTPLUS) {
                v += bias[gn];
                v = fmaxf(v, 0.f) + log1pf(expf(-fabsf(v)));  // softplus
            }
            size_t off = (size_t)gm * ldc + gn;
            if (C_BF) {
                ((ushortT*)Cv)[off] = f2bf(v);
            } else {
                float* p = (float*)Cv + off;
                *p = (EPI == EPI_ADD) ? v + *p : v;
            }
        }
    }
}

// ----------------------------------------------------------------------------
// RMSNorm: xn[r,:] = x[r,:] * rsqrt(mean(x^2)+1e-5) * w   (768/row, bf16 out)
// ----------------------------------------------------------------------------
__global__ __launch_bounds__(256)
void rmsnorm_kernel(const float* __restrict__ x, const float* __restrict__ w,
                    ushortT* __restrict__ xn)
{
    int r = blockIdx.x;
    const float* xr = x + (size_t)r * DM;
    float v[3];
    float s = 0.f;
#pragma unroll
    for (int i = 0; i < 3; ++i) {
        v[i] = xr[threadIdx.x + i * 256];
        s += v[i] * v[i];
    }
#pragma unroll
    for (int o = 32; o > 0; o >>= 1) s += __shfl_down(s, o, 64);
    __shared__ float wsum[4];
    __shared__ float scale_s;
    int wave = threadIdx.x >> 6;
    if ((threadIdx.x & 63) == 0) wsum[wave] = s;
    __syncthreads();
    if (threadIdx.x == 0) {
        float t = wsum[0] + wsum[1] + wsum[2] + wsum[3];
        scale_s = rsqrtf(t * (1.f / 768.f) + 1e-5f);
    }
    __syncthreads();
    float sc = scale_s;
#pragma unroll
    for (int i = 0; i < 3; ++i) {
        int d = threadIdx.x + i * 256;
        xn[(size_t)r * DM + d] = f2bf(v[i] * sc * w[d]);
    }
}

// ----------------------------------------------------------------------------
// Causal depthwise conv (width 4) + bias + silu.
// ----------------------------------------------------------------------------
__global__ __launch_bounds__(256)
void conv_silu_kernel(const ushortT* __restrict__ xc, const float* __restrict__ cw,
                      const float* __restrict__ cb, ushortT* __restrict__ xin)
{
    int idx = blockIdx.x * 256 + threadIdx.x;
    if (idx >= ROWS * ED) return;
    int e = idx % ED;
    int r = idx / ED;
    int l = r % L_TOK;
    float w0 = cw[e * 4 + 0], w1 = cw[e * 4 + 1];
    float w2 = cw[e * 4 + 2], w3 = cw[e * 4 + 3];
    const ushortT* base = xc + (size_t)r * ED + e;
    float acc = cb[e] + w3 * bf2f(base[0]);
    if (l >= 1) acc += w2 * bf2f(base[-(ptrdiff_t)ED]);
    if (l >= 2) acc += w1 * bf2f(base[-(ptrdiff_t)(2 * ED)]);
    if (l >= 3) acc += w0 * bf2f(base[-(ptrdiff_t)(3 * ED)]);
    xin[(size_t)r * ED + e] = f2bf(acc / (1.f + __expf(-acc)));  // silu
}

// ----------------------------------------------------------------------------
// Selective scan, fused with +D*xin and *silu(z).
// Block = 256 threads = 16 channels x 16 states.
// ----------------------------------------------------------------------------
__global__ __launch_bounds__(256)
void scan_kernel(const ushortT* __restrict__ delta, const ushortT* __restrict__ xin,
                 const float* __restrict__ dbc, const ushortT* __restrict__ zb,
                 const float* __restrict__ a_log, const float* __restrict__ dvec,
                 ushortT* __restrict__ y)
{
    int tid = threadIdx.x;
    int n  = tid & 15;
    int el = tid >> 4;
    int b  = blockIdx.x / (ED / 16);
    int e  = (blockIdx.x % (ED / 16)) * 16 + el;

    float a   = -expf(a_log[e * NST + n]);   // A = -exp(A_log)
    float dcf = dvec[e];
    float h = 0.f;

    int r = b * L_TOK;
    float dl = bf2f(delta[(size_t)r * ED + e]);
    float xi = bf2f(xin[(size_t)r * ED + e]);
    float Bn = dbc[r * 80 + 48 + n];
    float Cn = dbc[r * 80 + 64 + n];
    float z  = bf2f(zb[(size_t)r * ED + e]);

    for (int l = 0; l < L_TOK; ++l) {
        int rn = r + 1;
        float dl2 = 0.f, xi2 = 0.f, Bn2 = 0.f, Cn2 = 0.f, z2 = 0.f;
        if (l + 1 < L_TOK) {   // prefetch next step
            dl2 = bf2f(delta[(size_t)rn * ED + e]);
            xi2 = bf2f(xin[(size_t)rn * ED + e]);
            Bn2 = dbc[rn * 80 + 48 + n];
            Cn2 = dbc[rn * 80 + 64 + n];
            z2  = bf2f(zb[(size_t)rn * ED + e]);
        }
        float dA = __expf(dl * a);
        h = dA * h + dl * xi * Bn;
        float p = h * Cn;
        p += __shfl_xor(p, 1);
        p += __shfl_xor(p, 2);
        p += __shfl_xor(p, 4);
        p += __shfl_xor(p, 8);
        if (n == 0) {
            float yv = p + dcf * xi;
            float sz = z / (1.f + __expf(-z));
            y[(size_t)r * ED + e] = f2bf(yv * sz);
        }
        dl = dl2; xi = xi2; Bn = Bn2; Cn = Cn2; z = z2;
        r = rn;
    }
}

// ----------------------------------------------------------------------------
// im2col for patch embed: P[r, k] (bf16) with r=(b, img, patch), k=(c,ph,pw)
// ----------------------------------------------------------------------------
__global__ __launch_bounds__(256)
void im2col_kernel(const float* __restrict__ rgb, const float* __restrict__ timg,
                   ushortT* __restrict__ P)
{
    int idx = blockIdx.x * 256 + threadIdx.x;
    if (idx >= ROWS * DM) return;
    int k = idx % DM;
    int r = idx / DM;
    int b = r / L_TOK;
    int l = r % L_TOK;
    const float* img = (l < 196) ? rgb : timg;
    int p  = (l < 196) ? l : l - 196;
    int py = p / 14, px = p % 14;
    int c  = k >> 8;
    int ph = (k >> 4) & 15;
    int pw = k & 15;
    P[idx] = f2bf(img[(((size_t)b * 3 + c) * 224 + (py * 16 + ph)) * 224 + (px * 16 + pw)]);
}

// ----------------------------------------------------------------------------
// Output: out[(l*768 + d)*8 + b] = x[b, l, d]
// ----------------------------------------------------------------------------
__global__ __launch_bounds__(256)
void out_transpose_kernel(const float* __restrict__ x, float* __restrict__ out)
{
    int idx = blockIdx.x * 256 + threadIdx.x;
    if (idx >= ROWS * DM) return;
    int b = idx & 7;
    int d = (idx >> 3) % DM;
    int l = idx / (8 * DM);
    out[idx] = x[((size_t)(b * L_TOK + l)) * DM + d];
}

// ----------------------------------------------------------------------------
extern "C" void kernel_launch(void* const* d_in, const int* in_sizes, int n_in,
                              void* d_out, int out_size, void* d_ws, size_t ws_size,
                              hipStream_t stream)
{
    (void)in_sizes; (void)n_in; (void)out_size; (void)ws_size;

    const float* rgb  = (const float*)d_in[0];
    const float* timg = (const float*)d_in[1];
    const float* pe_w = (const float*)d_in[2];   // [768, 3,16,16] -> [768][768]
    const float* pe_b = (const float*)d_in[3];
    const float* in_w = (const float*)d_in[4];   // [8, 3072, 768]
    const float* cw   = (const float*)d_in[5];   // [8, 1536, 1, 4]
    const float* cb   = (const float*)d_in[6];   // [8, 1536]
    const float* xw   = (const float*)d_in[7];   // [8, 80, 1536]
    const float* dtw  = (const float*)d_in[8];   // [8, 1536, 48]
    const float* dtb  = (const float*)d_in[9];   // [8, 1536]
    const float* alog = (const float*)d_in[10];  // [8, 1536, 16]
    const float* dvec = (const float*)d_in[11];  // [8, 1536]
    const float* ow   = (const float*)d_in[12];  // [8, 768, 1536]
    const float* nw   = (const float*)d_in[13];  // [8, 768]

    char* p = (char*)d_ws;
    float*   X   = (float*)p;    p += (size_t)ROWS * DM * 4;
    ushortT* XC  = (ushortT*)p;  p += (size_t)ROWS * ED * 2;   // conv-in / patches / y
    ushortT* Zb  = (ushortT*)p;  p += (size_t)ROWS * ED * 2;
    ushortT* XIN = (ushortT*)p;  p += (size_t)ROWS * ED * 2;
    ushortT* DEL = (ushortT*)p;  p += (size_t)ROWS * ED * 2;   // delta; front = xn
    float*   DBC = (float*)p;    p += (size_t)ROWS * 80 * 4;
    ushortT* XN  = DEL;          // overlay: xn dead before delta is written

    dim3 b256(256);
    const int MT = (ROWS + 127) / 128;   // 25 M-tiles

    // ---- patch embed: im2col (bf16) into XC, then MFMA GEMM+bias -> X ----
    im2col_kernel<<<(ROWS * DM + 255) / 256, b256, 0, stream>>>(rgb, timg, XC);
    gemm_mfma<EPI_BIAS, false><<<dim3(DM / 128, MT), b256, 0, stream>>>(
        XC, DM, pe_w, DM, pe_b, X, DM, ROWS, DM, DM);

    for (int i = 0; i < 8; ++i) {
        const float* in_wi = in_w + (size_t)i * 2 * ED * DM;
        const float* cwi   = cw   + (size_t)i * ED * 4;
        const float* cbi   = cb   + (size_t)i * ED;
        const float* xwi   = xw   + (size_t)i * 80 * ED;
        const float* dtwi  = dtw  + (size_t)i * ED * DTR;
        const float* dtbi  = dtb  + (size_t)i * ED;
        const float* ali   = alog + (size_t)i * ED * NST;
        const float* dvi   = dvec + (size_t)i * ED;
        const float* owi   = ow   + (size_t)i * DM * ED;
        const float* nwi   = nw   + (size_t)i * DM;

        // xn = rmsnorm(x)  -> XN (bf16, overlaid on DEL)
        rmsnorm_kernel<<<ROWS, b256, 0, stream>>>(X, nwi, XN);
        // xc = xn @ in_w[:ED]^T ; z = xn @ in_w[ED:]^T   (MFMA)
        gemm_mfma<EPI_STORE, true><<<dim3(ED / 128, MT), b256, 0, stream>>>(
            XN, DM, in_wi, DM, nullptr, XC, ED, ROWS, ED, DM);
        gemm_mfma<EPI_STORE, true><<<dim3(ED / 128, MT), b256, 0, stream>>>(
            XN, DM, in_wi + (size_t)ED * DM, DM, nullptr, Zb, ED, ROWS, ED, DM);
        // xin = silu(causal_conv(xc) + cb)
        conv_silu_kernel<<<(ROWS * ED + 255) / 256, b256, 0, stream>>>(
            XC, cwi, cbi, XIN);
        // dbc = xin @ xw^T  -> DBC fp32 [3136,80]   (VALU: N=80)
        gemm_nt<EPI_STORE, true, false><<<dim3(2, ROWS / 64), b256, 0, stream>>>(
            XIN, ED, xwi, ED, nullptr, DBC, 80, ROWS, 80, ED);
        // delta = softplus(dbc[:, :48] @ dtw^T + dtb) -> DEL bf16   (VALU: K=48)
        gemm_nt<EPI_BIAS_SOFTPLUS, false, true><<<dim3(ED / 64, ROWS / 64), b256, 0, stream>>>(
            DBC, 80, dtwi, DTR, dtbi, DEL, ED, ROWS, ED, DTR);
        // y = scan(...) fused +D*xin, *silu(z)  -> XC
        scan_kernel<<<BATCH * (ED / 16), b256, 0, stream>>>(
            DEL, XIN, DBC, Zb, ali, dvi, XC);
        // x += y @ ow^T   (MFMA)
        gemm_mfma<EPI_ADD, false><<<dim3(DM / 128, MT), b256, 0, stream>>>(
            XC, ED, owi, ED, nullptr, X, DM, ROWS, DM, ED);
    }

    out_transpose_kernel<<<(ROWS * DM + 255) / 256, b256, 0, stream>>>(
        X, (float*)d_out);
}